// Round 14
// baseline (1246.656 us; speedup 1.0000x reference)
//
#include <hip/hip_runtime.h>
#include <stdint.h>
#include <stddef.h>

// Problem dims
#define B_  128
#define S_  48
#define E_  620
#define EP  640
#define H_  2400
#define N3  7200   // 3*H (r,i,n concatenated)
#define KH  2400
#define P1_ITERS 20  // phase-1 K = 640 = 20 x 32
#define KZ   5       // phase-2 cross-block K-split (480 k each)
#define KZI  15      // k-iters per block (480 / 32)
#define UG   48      // hidden units per group (3 nw x 16)
#define NG   50      // unit groups (H_/UG)
// Lane-major packed geometry (halves): one 16-row x 32-k chunk = 512 halves
// laid out so each wave's MFMA fragment load is one contiguous 1024-B access.
#define WCHUNK 512            // one plane chunk
#define WIT    (9 * WCHUNK)   // W halves per k-iter per (g,kz): 3 nw x 3 planes
#define ACH    4096           // A halves per k-iter: [mw4][mf2][lane64][8]
#define AHB    2048           // A halves per k-iter per HALF-block (2 mw)
#define KTL    (AHB + WIT)    // halves per kt in LDS (6656)
#define NBP  57               // Wi packed n-blocks (7296 rows, zero-padded)

typedef _Float16 half_t;
typedef __attribute__((ext_vector_type(8))) _Float16 half8;
typedef __attribute__((ext_vector_type(4))) _Float16 half4;
typedef __attribute__((ext_vector_type(4))) float    floatx4;

// Workgroup barrier that waits ONLY on LDS ops; in-flight global loads keep
// flying. 0xC07F = vmcnt(63) expcnt(7) lgkmcnt(0).
__device__ __forceinline__ void lds_barrier() {
  __builtin_amdgcn_sched_barrier(0);
  __builtin_amdgcn_s_waitcnt(0xC07F);
  __builtin_amdgcn_s_barrier();
  __builtin_amdgcn_sched_barrier(0);
}

// u-map shared by phase-1 packing and gemm_x staging: unit u in [0,512)
// covers (row-in-128-block, q) as row = (u>>6)*16 + (u&15),
// q(k-offset/8 within 32-k tile) = (u>>4)&3.
__device__ __forceinline__ int umap(int mr, int c0) {
  return ((mr >> 4) << 6) | (((c0 & 31) >> 3) << 4) | (mr & 15);
}

// ---- xp = fp16(emb[tokens]) packed lane-major [mb48][kt20][u512][8] ----
__global__ void gather_cast_x(const int* __restrict__ tokens,
                              const float* __restrict__ emb,
                              half_t* __restrict__ xp) {
  int idx = blockIdx.x * 256 + threadIdx.x;       // over 6144 * 80
  int m = idx / 80;
  int c0 = (idx - m * 80) * 8;
  int tok = tokens[m];
  half8 v{};
  #pragma unroll
  for (int e = 0; e < 8; ++e) {
    int c = c0 + e;
    v[e] = (half_t)((c < E_) ? emb[(size_t)tok * E_ + c] : 0.f);
  }
  int mb = m >> 7, mr = m & 127, kt = c0 >> 5;
  *(half8*)(xp + ((size_t)(mb * P1_ITERS + kt) * 512 + umap(mr, c0)) * 8) = v;
}

// ---- Wip = fp16 concat(W_ir,W_ii,W_in) packed [nb57][kt20][512][8] ----
__global__ void convert_wi(const float* __restrict__ Wir, const float* __restrict__ Wii,
                           const float* __restrict__ Win,
                           const float* __restrict__ bir, const float* __restrict__ bii,
                           const float* __restrict__ bin,
                           half_t* __restrict__ Wip, float* __restrict__ bias) {
  int idx = blockIdx.x * 256 + threadIdx.x;       // over 7296 * 80
  int r = idx / 80;
  int c0 = (idx - r * 80) * 8;
  half8 v{};
  if (r < N3) {
    const float* W = (r < H_) ? Wir : (r < 2*H_ ? Wii : Win);
    int rr = (r < H_) ? r : (r < 2*H_ ? r - H_ : r - 2*H_);
    #pragma unroll
    for (int e = 0; e < 8; ++e) {
      int c = c0 + e;
      v[e] = (half_t)((c < E_) ? W[(size_t)rr * E_ + c] : 0.f);
    }
    if (c0 == 0) {
      const float* bb = (r < H_) ? bir : (r < 2*H_ ? bii : bin);
      bias[r] = bb[rr];
    }
  }
  int nb = r >> 7, mr = r & 127, kt = c0 >> 5;
  *(half8*)(Wip + ((size_t)(nb * P1_ITERS + kt) * 512 + umap(mr, c0)) * 8) = v;
}

// ---- Wp = fp16 PACKED recurrent weights, lane-major chunks ----
// Wp[g50][kz5][kt15][chunk9 = nw*3+plane][lane64][e8]. half8 read + write.
__global__ void convert_wh(const float* __restrict__ Whr, const float* __restrict__ Whi,
                           const float* __restrict__ Whn, half_t* __restrict__ Wp) {
  int idx = blockIdx.x * 256 + threadIdx.x;       // over 7200 * 300
  if (idx >= N3 * (KH / 8)) return;
  int r3 = idx / 300;
  int c0 = (idx - r3 * 300) * 8;
  const float* W = (r3 < H_) ? Whr : (r3 < 2*H_ ? Whi : Whn);
  int p  = (r3 < H_) ? 0 : (r3 < 2*H_ ? 1 : 2);
  int rr = r3 - p * H_;
  int g = rr / UG, u = rr - g * UG;
  int nw = u >> 4, fm = u & 15;
  int kz = c0 / 480, rem = c0 - kz * 480, kt = rem >> 5, ksub = c0 & 31;
  half8 v;
  #pragma unroll
  for (int e = 0; e < 8; ++e) v[e] = (half_t)W[(size_t)rr * KH + c0 + e];
  size_t chunk = ((size_t)(g * KZ + kz) * KZI + kt) * 9 + (nw * 3 + p);
  *(half8*)(Wp + chunk * WCHUNK + ((size_t)((ksub >> 3) * 16 + fm)) * 8) = v;
}

__global__ void init_h(float* __restrict__ h, half_t* __restrict__ Ap) {
  int idx = blockIdx.x * 256 + threadIdx.x;       // over B_*H_
  h[idx] = 0.f;
  Ap[idx] = (half_t)0.f;
}

// ---- Phase 1: gx = fp16( xp @ Wip^T + bias )  [6144 x 7200], K=640 ----
// (round-12 structure: lane-major packed staging, LDS-transposed epilogue)
__global__ __launch_bounds__(256, 4) void gemm_x(
    const half_t* __restrict__ A,   // xp packed [48][20][512][8]
    const half_t* __restrict__ Bm,  // Wip packed [57][20][512][8]
    half_t* __restrict__ C,         // gx [6144 x 7200]
    const float* __restrict__ bias)
{
  __shared__ half_t SH[17408];   // staging: A [2][4096] @0, B [2][4096] @8192
                                 // epilogue: C-tile 128 x 136

  const int tid = threadIdx.x;
  const int lane = tid & 63;
  const int w = tid >> 6;
  const int m0 = blockIdx.x * 128;
  const int n0 = blockIdx.y * 128;
  const int wm = (w >> 1) * 64, wn = (w & 1) * 64;

  const int c0 = tid, c1 = tid + 256;
  const half_t* pA0 = A  + ((size_t)blockIdx.x * P1_ITERS * 512 + c0) * 8;
  const half_t* pA1 = A  + ((size_t)blockIdx.x * P1_ITERS * 512 + c1) * 8;
  const half_t* pB0 = Bm + ((size_t)blockIdx.y * P1_ITERS * 512 + c0) * 8;
  const half_t* pB1 = Bm + ((size_t)blockIdx.y * P1_ITERS * 512 + c1) * 8;

  floatx4 acc[4][4] = {};

  half8 ga0 = *(const half8*)(pA0);
  half8 ga1 = *(const half8*)(pA1);
  half8 gb0 = *(const half8*)(pB0);
  half8 gb1 = *(const half8*)(pB1);
  *(half8*)(SH + c0 * 8) = ga0;
  *(half8*)(SH + c1 * 8) = ga1;
  *(half8*)(SH + 8192 + c0 * 8) = gb0;
  *(half8*)(SH + 8192 + c1 * 8) = gb1;
  ga0 = *(const half8*)(pA0 + 4096);
  ga1 = *(const half8*)(pA1 + 4096);
  gb0 = *(const half8*)(pB0 + 4096);
  gb1 = *(const half8*)(pB1 + 4096);
  lds_barrier();

  #pragma unroll
  for (int i = 0; i < P1_ITERS; ++i) {
    const int cur = i & 1, nxt = cur ^ 1;
    half8 a[4], b[4];
    #pragma unroll
    for (int f = 0; f < 4; ++f) {
      a[f] = *(const half8*)(SH + cur * 4096 + (((wm >> 4) + f) * 64 + lane) * 8);
      b[f] = *(const half8*)(SH + 8192 + cur * 4096 + (((wn >> 4) + f) * 64 + lane) * 8);
    }
    if (i + 1 < P1_ITERS) {
      *(half8*)(SH + nxt * 4096 + c0 * 8) = ga0;
      *(half8*)(SH + nxt * 4096 + c1 * 8) = ga1;
      *(half8*)(SH + 8192 + nxt * 4096 + c0 * 8) = gb0;
      *(half8*)(SH + 8192 + nxt * 4096 + c1 * 8) = gb1;
    }
    if (i + 2 < P1_ITERS) {
      size_t ko = (size_t)(i + 2) * 4096;
      ga0 = *(const half8*)(pA0 + ko);
      ga1 = *(const half8*)(pA1 + ko);
      gb0 = *(const half8*)(pB0 + ko);
      gb1 = *(const half8*)(pB1 + ko);
    }
    #pragma unroll
    for (int mf = 0; mf < 4; ++mf)
      #pragma unroll
      for (int nf = 0; nf < 4; ++nf)
        acc[mf][nf] = __builtin_amdgcn_mfma_f32_16x16x32_f16(
            a[mf], b[nf], acc[mf][nf], 0, 0, 0);
    if (i + 1 < P1_ITERS) lds_barrier();
  }

  // Epilogue: acc -> LDS (fp16, +bias) -> row-contiguous coalesced stores.
  __syncthreads();
  const int col = lane & 15, qr = (lane >> 4) * 4;
  #pragma unroll
  for (int nf = 0; nf < 4; ++nf) {
    const int cloc = wn + nf * 16 + col;
    const int n = n0 + cloc;
    const float bv = (n < N3) ? bias[n] : 0.f;
    #pragma unroll
    for (int mf = 0; mf < 4; ++mf)
      #pragma unroll
      for (int r = 0; r < 4; ++r)
        SH[(wm + mf * 16 + qr + r) * 136 + cloc] =
            (half_t)(acc[mf][nf][r] + bv);
  }
  __syncthreads();
  const int row = tid >> 1, cc = (tid & 1) * 64;
  half_t* crow = C + (size_t)(m0 + row) * N3;
  #pragma unroll
  for (int j = 0; j < 8; ++j) {
    const int nn = n0 + cc + j * 8;
    half8 vv = *(const half8*)(SH + row * 136 + cc + j * 8);
    if (nn + 8 <= N3) {
      *(half8*)(crow + nn) = vv;
    } else if (nn < N3) {
      for (int e = 0; e < N3 - nn; ++e) crow[nn + e] = vv[e];
    }
  }
}

// ---- Phase 2a: recurrent GEMM partials, grid (50 g, 5 kz, 2 z) x 384. ----
// Round-14: the 12-wave block is split into TWO co-residable 6-wave blocks
// (2 mw x 3 nw each, 64 batch rows), grid 500 ~ 2 blocks/CU: when one
// block's waves convoy at the lds_barrier, the other block's MFMA phase
// fills the CU (inter-block overlap -- the TLP axis intra-block depth
// (r11-null) and barrier count (r13-negative) could not provide). Pipeline,
// per-wave code, and arithmetic identical to round-12's triple-buffer.
// LDS: 3 bufs x 6656 halves = 39 KB.
__global__ __launch_bounds__(384, 3) void gru_gemm(
    const half_t* __restrict__ Ap_old,  // [75 kt][4 mw][2 mf][512] lane-major
    const half_t* __restrict__ Wp,      // [50][5][15][9][512] lane-major
    half_t* __restrict__ Gp)            // partials [5 kz][128 b][3 p][2400 j]
{
  __shared__ half_t S[3][KTL];   // per buf: A 2048 halves | W 4608 halves

  const int tid  = threadIdx.x;
  const int lane = tid & 63;
  const int w    = tid >> 6;        // 0..5
  const int mwl  = w & 1;           // local batch stripe (32 rows)
  const int nw   = w >> 1;          // unit-16 sub-group (0..2)
  const int g    = blockIdx.x;      // 0..49
  const int kz   = blockIdx.y;      // 0..4
  const int z    = blockIdx.z;      // 0..1 (batch half)

  const half_t* Asrc = Ap_old + (size_t)kz * KZI * ACH + z * AHB;
  const half_t* Wsrc = Wp + (size_t)(g * KZ + kz) * KZI * WIT;

  // Staging: 832 16-B units per kt (A 256 | W 576). Thread covers
  // u = tid, u = 384+tid, and (tid<64) u = 768+tid. dst = u*8.
  const bool tail = (tid < 64);
  const half_t* src0 = (tid < 256) ? (Asrc + tid * 8) : (Wsrc + (tid - 256) * 8);
  const int     str0 = (tid < 256) ? ACH : WIT;
  const half_t* src1 = Wsrc + (size_t)(tid + 128) * 8;   // units 384..767
  const half_t* src2 = Wsrc + (size_t)(tid + 512) * 8;   // units 768..831
  const int d0 = tid * 8;
  const int d1 = 3072 + tid * 8;
  const int d2 = 6144 + tid * 8;

  // Prologue: fill buf0 (kt0), buf1 (kt1); pending regs kt2, kt3.
  half8 p0 = *(const half8*)(src0);
  half8 q0 = *(const half8*)(src1);
  half8 t0{}; if (tail) t0 = *(const half8*)(src2);
  half8 p1 = *(const half8*)(src0 + str0);
  half8 q1 = *(const half8*)(src1 + WIT);
  half8 t1{}; if (tail) t1 = *(const half8*)(src2 + WIT);
  *(half8*)(&S[0][d0]) = p0;
  *(half8*)(&S[0][d1]) = q0;
  if (tail) *(half8*)(&S[0][d2]) = t0;
  *(half8*)(&S[1][d0]) = p1;
  *(half8*)(&S[1][d1]) = q1;
  if (tail) *(half8*)(&S[1][d2]) = t1;
  half8 rp0 = *(const half8*)(src0 + 2 * (size_t)str0);   // kt2 (write at i=0)
  half8 rq0 = *(const half8*)(src1 + 2 * (size_t)WIT);
  half8 rt0{}; if (tail) rt0 = *(const half8*)(src2 + 2 * (size_t)WIT);
  half8 rp1 = *(const half8*)(src0 + 3 * (size_t)str0);   // kt3 (write at i=1)
  half8 rq1 = *(const half8*)(src1 + 3 * (size_t)WIT);
  half8 rt1{}; if (tail) rt1 = *(const half8*)(src2 + 3 * (size_t)WIT);
  lds_barrier();

  floatx4 acc[2][3] = {};   // [mf][plane]
  const int aoff0 = (mwl * 2 + 0) * 512 + lane * 8;
  const int aoff1 = (mwl * 2 + 1) * 512 + lane * 8;
  const int woff  = AHB + nw * 3 * 512 + lane * 8;

  #pragma unroll
  for (int i = 0; i < KZI; ++i) {
    const int cur = i % 3, wb = (i + 2) % 3;
    half8 a0 = *(const half8*)(&S[cur][aoff0]);
    half8 a1 = *(const half8*)(&S[cur][aoff1]);
    half8 b0 = *(const half8*)(&S[cur][woff]);
    half8 b1 = *(const half8*)(&S[cur][woff + 512]);
    half8 b2 = *(const half8*)(&S[cur][woff + 1024]);
    if (i + 2 < KZI) {                       // ds_write kt=i+2 (loaded i-2)
      *(half8*)(&S[wb][d0]) = rp0;
      *(half8*)(&S[wb][d1]) = rq0;
      if (tail) *(half8*)(&S[wb][d2]) = rt0;
    }
    rp0 = rp1; rq0 = rq1; rt0 = rt1;
    if (i + 4 < KZI) {                       // issue load kt=i+4
      rp1 = *(const half8*)(src0 + (size_t)(i + 4) * str0);
      rq1 = *(const half8*)(src1 + (size_t)(i + 4) * WIT);
      if (tail) rt1 = *(const half8*)(src2 + (size_t)(i + 4) * WIT);
    }
    acc[0][0] = __builtin_amdgcn_mfma_f32_16x16x32_f16(a0, b0, acc[0][0], 0, 0, 0);
    acc[1][0] = __builtin_amdgcn_mfma_f32_16x16x32_f16(a1, b0, acc[1][0], 0, 0, 0);
    acc[0][1] = __builtin_amdgcn_mfma_f32_16x16x32_f16(a0, b1, acc[0][1], 0, 0, 0);
    acc[1][1] = __builtin_amdgcn_mfma_f32_16x16x32_f16(a1, b1, acc[1][1], 0, 0, 0);
    acc[0][2] = __builtin_amdgcn_mfma_f32_16x16x32_f16(a0, b2, acc[0][2], 0, 0, 0);
    acc[1][2] = __builtin_amdgcn_mfma_f32_16x16x32_f16(a1, b2, acc[1][2], 0, 0, 0);
    if (i + 1 < KZI) lds_barrier();
  }

  // fp16 partial store. C-layout: col = lane&15 (unit), row = batch.
  const int j  = g * UG + nw * 16 + (lane & 15);
  const int wm = (z * 2 + mwl) * 32;
  const int qr = (lane >> 4) * 4;
  #pragma unroll
  for (int mf = 0; mf < 2; ++mf)
    #pragma unroll
    for (int p = 0; p < 3; ++p)
      #pragma unroll
      for (int r = 0; r < 4; ++r) {
        const int b = wm + mf * 16 + qr + r;
        Gp[((size_t)(kz * B_ + b) * 3 + p) * H_ + j] = (half_t)acc[mf][p][r];
      }
}

// ---- Phase 2b: gate update. grid 600 x 64; thread = (b, 8 units). ----
// half8 loads throughout; 64-thread blocks spread 600 blocks ~2.3/CU.
__global__ void gru_gate(
    const half_t* __restrict__ Gp,      // [5][128][3][2400]
    const half_t* __restrict__ gx,      // [6144 x 7200]
    const float* __restrict__ hold,     // [B][H] fp32
    float* __restrict__ hnew,
    half_t* __restrict__ Ap_new,        // packed hh, lane-major
    const int* __restrict__ lengths,
    float* __restrict__ out,            // [B][H]
    int t)
{
  const int idx = blockIdx.x * 64 + threadIdx.x;   // over 128 * 300
  const int b = idx / 300;
  const int j = (idx - b * 300) * 8;

  float G[3][8] = {};
  #pragma unroll
  for (int kz = 0; kz < KZ; ++kz)
    #pragma unroll
    for (int p = 0; p < 3; ++p) {
      half8 v = *(const half8*)(Gp + ((size_t)(kz * B_ + b) * 3 + p) * H_ + j);
      #pragma unroll
      for (int e = 0; e < 8; ++e) G[p][e] += (float)v[e];
    }

  const size_t rx = ((size_t)b * S_ + t) * N3 + j;
  half8 hxr = *(const half8*)(gx + rx);
  half8 hxi = *(const half8*)(gx + rx + H_);
  half8 hxn = *(const half8*)(gx + rx + 2 * H_);
  floatx4 ho0 = *(const floatx4*)(hold + (size_t)b * H_ + j);
  floatx4 ho1 = *(const floatx4*)(hold + (size_t)b * H_ + j + 4);

  floatx4 hv0, hv1;
  half8 ap8;
  #pragma unroll
  for (int e = 0; e < 8; ++e) {
    const float hoe = (e < 4) ? ho0[e] : ho1[e - 4];
    const float rg = 1.f / (1.f + __expf(-((float)hxr[e] + G[0][e])));
    const float ig = 1.f / (1.f + __expf(-((float)hxi[e] + G[1][e])));
    const float ta = (float)hxn[e] + rg * G[2][e];
    const float nn = 1.f - 2.f / (1.f + __expf(2.f * ta));  // tanh(ta)
    const float hv = (1.f - ig) * nn + ig * hoe;
    if (e < 4) hv0[e] = hv; else hv1[e - 4] = hv;
    ap8[e] = (half_t)hv;
  }
  *(floatx4*)(hnew + (size_t)b * H_ + j)     = hv0;
  *(floatx4*)(hnew + (size_t)b * H_ + j + 4) = hv1;

  // lane-major packed-A store: 8 units j..j+7 are contiguous in the chunk.
  const int kt = j >> 5, ksub = j & 31;
  const int mwb = b >> 5, rb = b & 31, mfb = rb >> 4, fmb = rb & 15;
  const size_t pos = (size_t)kt * ACH + (mwb * 2 + mfb) * 512
                   + ((size_t)((ksub >> 3) * 16 + fmb)) * 8;
  *(half8*)(Ap_new + pos) = ap8;

  int lc = lengths[b] - 1;
  lc = lc < 0 ? 0 : (lc > S_ - 1 ? S_ - 1 : lc);
  if (t == lc) {
    *(floatx4*)(out + (size_t)b * H_ + j)     = hv0;
    *(floatx4*)(out + (size_t)b * H_ + j + 4) = hv1;
  }
}

extern "C" void kernel_launch(void* const* d_in, const int* in_sizes, int n_in,
                              void* d_out, int out_size, void* d_ws, size_t ws_size,
                              hipStream_t stream)
{
  const int*   tokens  = (const int*)d_in[0];
  const int*   lengths = (const int*)d_in[1];
  const float* emb = (const float*)d_in[2];
  const float* Wir = (const float*)d_in[3];
  const float* Wii = (const float*)d_in[4];
  const float* Win = (const float*)d_in[5];
  const float* bir = (const float*)d_in[6];
  const float* bii = (const float*)d_in[7];
  const float* bin = (const float*)d_in[8];
  const float* Whr = (const float*)d_in[9];
  const float* Whi = (const float*)d_in[10];
  const float* Whn = (const float*)d_in[11];
  float* out = (float*)d_out;

  char* ws = (char*)d_ws;
  size_t off = 0;
  auto alloc = [&](size_t bytes) {
    void* p = ws + off;
    off = (off + bytes + 255) & ~(size_t)255;
    return p;
  };
  half_t* xp   = (half_t*)alloc((size_t)48 * P1_ITERS * 512 * 8 * 2);   //  7.9 MB
  half_t* Wip  = (half_t*)alloc((size_t)NBP * P1_ITERS * 512 * 8 * 2);  //  9.3 MB
  half_t* Wp   = (half_t*)alloc((size_t)N3 * KH * 2);          // 34.6 MB packed
  float*  bias = (float*)alloc((size_t)N3 * 4);
  half_t* gx   = (half_t*)alloc((size_t)(B_ * S_) * N3 * 2);   // 88.5 MB
  half_t* Gp   = (half_t*)alloc((size_t)KZ * B_ * N3 * 2);     //  9.2 MB fp16
  float*  h0   = (float*)alloc((size_t)B_ * H_ * 4);           // ping-pong h [B][H]
  float*  h1   = (float*)alloc((size_t)B_ * H_ * 4);
  half_t* Ap0  = (half_t*)alloc((size_t)B_ * H_ * 2);          // packed hh
  half_t* Ap1  = (half_t*)alloc((size_t)B_ * H_ * 2);

  gather_cast_x<<<(6144 * 80) / 256, 256, 0, stream>>>(tokens, emb, xp);
  convert_wi<<<(7296 * 80) / 256, 256, 0, stream>>>(Wir, Wii, Win, bir, bii, bin,
                                                    Wip, bias);
  convert_wh<<<(N3 * 300 + 255) / 256, 256, 0, stream>>>(Whr, Whi, Whn, Wp);
  init_h<<<(B_ * H_) / 256, 256, 0, stream>>>(h0, Ap0);

  // Phase 1: gates_x = fp16( x @ W_i^T + b )   [6144 x 7200]
  gemm_x<<<dim3(48, NBP), 256, 0, stream>>>(xp, Wip, gx, bias);

  // Phase 2: 48 GRU steps x {500-block GEMM (2/CU), 600-block gate}
  for (int t = 0; t < S_; ++t) {
    const half_t* ai = (t & 1) ? Ap1 : Ap0;
    half_t*       aw = (t & 1) ? Ap0 : Ap1;
    const float*  ho = (t & 1) ? h1  : h0;
    float*        hn = (t & 1) ? h0  : h1;
    gru_gemm<<<dim3(NG, KZ, 2), 384, 0, stream>>>(ai, Wp, Gp);
    gru_gate<<<(B_ * H_ / 8) / 64, 64, 0, stream>>>(
        Gp, gx, ho, hn, aw, lengths, out, t);
  }
}

// Round 15
// 1006.418 us; speedup vs baseline: 1.2387x; 1.2387x over previous
//
#include <hip/hip_runtime.h>
#include <stdint.h>
#include <stddef.h>

// Problem dims
#define B_  128
#define S_  48
#define E_  620
#define EP  640
#define H_  2400
#define N3  7200   // 3*H (r,i,n concatenated)
#define KH  2400
#define P1_ITERS 20  // phase-1 K = 640 = 20 x 32
#define KZ   5       // phase-2 cross-block K-split (480 k each)
#define KZI  15      // k-iters per block (480 / 32)
#define UG   48      // hidden units per group (3 nw x 16)
#define NG   50      // unit groups (H_/UG)
// Lane-major packed geometry (halves): one 16-row x 32-k chunk = 512 halves
// laid out so each wave's MFMA fragment load is one contiguous 1024-B access.
#define WCHUNK 512            // one plane chunk
#define WIT    (9 * WCHUNK)   // W halves per k-iter per (g,kz): 3 nw x 3 planes
#define ACH    4096           // A halves per k-iter: [mw4][mf2][lane64][8]
#define NBP  57               // Wi packed n-blocks (7296 rows, zero-padded)

typedef _Float16 half_t;
typedef __attribute__((ext_vector_type(8))) _Float16 half8;
typedef __attribute__((ext_vector_type(4))) _Float16 half4;
typedef __attribute__((ext_vector_type(4))) float    floatx4;

// Workgroup barrier that waits ONLY on LDS ops; in-flight global loads keep
// flying. 0xC07F = vmcnt(63) expcnt(7) lgkmcnt(0).
__device__ __forceinline__ void lds_barrier() {
  __builtin_amdgcn_sched_barrier(0);
  __builtin_amdgcn_s_waitcnt(0xC07F);
  __builtin_amdgcn_s_barrier();
  __builtin_amdgcn_sched_barrier(0);
}

// u-map shared by phase-1 packing and gemm_x staging: unit u in [0,512)
// covers (row-in-128-block, q) as row = (u>>6)*16 + (u&15),
// q(k-offset/8 within 32-k tile) = (u>>4)&3.
__device__ __forceinline__ int umap(int mr, int c0) {
  return ((mr >> 4) << 6) | (((c0 & 31) >> 3) << 4) | (mr & 15);
}

// ---- xp = fp16(emb[tokens]) packed lane-major [mb48][kt20][u512][8] ----
__global__ void gather_cast_x(const int* __restrict__ tokens,
                              const float* __restrict__ emb,
                              half_t* __restrict__ xp) {
  int idx = blockIdx.x * 256 + threadIdx.x;       // over 6144 * 80
  int m = idx / 80;
  int c0 = (idx - m * 80) * 8;
  int tok = tokens[m];
  half8 v{};
  #pragma unroll
  for (int e = 0; e < 8; ++e) {
    int c = c0 + e;
    v[e] = (half_t)((c < E_) ? emb[(size_t)tok * E_ + c] : 0.f);
  }
  int mb = m >> 7, mr = m & 127, kt = c0 >> 5;
  *(half8*)(xp + ((size_t)(mb * P1_ITERS + kt) * 512 + umap(mr, c0)) * 8) = v;
}

// ---- Wip = fp16 concat(W_ir,W_ii,W_in) packed [nb57][kt20][512][8] ----
// rows 7200..7295 zero (epilogue guards n >= N3). bias concat [7200].
__global__ void convert_wi(const float* __restrict__ Wir, const float* __restrict__ Wii,
                           const float* __restrict__ Win,
                           const float* __restrict__ bir, const float* __restrict__ bii,
                           const float* __restrict__ bin,
                           half_t* __restrict__ Wip, float* __restrict__ bias) {
  int idx = blockIdx.x * 256 + threadIdx.x;       // over 7296 * 80
  int r = idx / 80;
  int c0 = (idx - r * 80) * 8;
  half8 v{};
  if (r < N3) {
    const float* W = (r < H_) ? Wir : (r < 2*H_ ? Wii : Win);
    int rr = (r < H_) ? r : (r < 2*H_ ? r - H_ : r - 2*H_);
    #pragma unroll
    for (int e = 0; e < 8; ++e) {
      int c = c0 + e;
      v[e] = (half_t)((c < E_) ? W[(size_t)rr * E_ + c] : 0.f);
    }
    if (c0 == 0) {
      const float* bb = (r < H_) ? bir : (r < 2*H_ ? bii : bin);
      bias[r] = bb[rr];
    }
  }
  int nb = r >> 7, mr = r & 127, kt = c0 >> 5;
  *(half8*)(Wip + ((size_t)(nb * P1_ITERS + kt) * 512 + umap(mr, c0)) * 8) = v;
}

// ---- Wp = fp16 PACKED recurrent weights, lane-major chunks ----
// Wp[g50][kz5][kt15][chunk9 = nw*3+plane][lane64][e8]. half8 read + write.
__global__ void convert_wh(const float* __restrict__ Whr, const float* __restrict__ Whi,
                           const float* __restrict__ Whn, half_t* __restrict__ Wp) {
  int idx = blockIdx.x * 256 + threadIdx.x;       // over 7200 * 300
  if (idx >= N3 * (KH / 8)) return;
  int r3 = idx / 300;
  int c0 = (idx - r3 * 300) * 8;
  const float* W = (r3 < H_) ? Whr : (r3 < 2*H_ ? Whi : Whn);
  int p  = (r3 < H_) ? 0 : (r3 < 2*H_ ? 1 : 2);
  int rr = r3 - p * H_;
  int g = rr / UG, u = rr - g * UG;
  int nw = u >> 4, fm = u & 15;
  int kz = c0 / 480, rem = c0 - kz * 480, kt = rem >> 5, ksub = c0 & 31;
  half8 v;
  #pragma unroll
  for (int e = 0; e < 8; ++e) v[e] = (half_t)W[(size_t)rr * KH + c0 + e];
  size_t chunk = ((size_t)(g * KZ + kz) * KZI + kt) * 9 + (nw * 3 + p);
  *(half8*)(Wp + chunk * WCHUNK + ((size_t)((ksub >> 3) * 16 + fm)) * 8) = v;
}

__global__ void init_h(float* __restrict__ h, half_t* __restrict__ Ap) {
  int idx = blockIdx.x * 256 + threadIdx.x;       // over B_*H_
  h[idx] = 0.f;
  Ap[idx] = (half_t)0.f;
}

// ---- Phase 1: gx = fp16( xp @ Wip^T + bias )  [6144 x 7200], K=640 ----
// Lane-major packed staging (contiguous 4-KB wave streams) + LDS-transposed
// epilogue (row-contiguous half8 stores). Measured 84.5 us, MfmaUtil 28%.
__global__ __launch_bounds__(256, 4) void gemm_x(
    const half_t* __restrict__ A,   // xp packed [48][20][512][8]
    const half_t* __restrict__ Bm,  // Wip packed [57][20][512][8]
    half_t* __restrict__ C,         // gx [6144 x 7200]
    const float* __restrict__ bias)
{
  __shared__ half_t SH[17408];   // staging: A [2][4096] @0, B [2][4096] @8192
                                 // epilogue: C-tile 128 x 136

  const int tid = threadIdx.x;
  const int lane = tid & 63;
  const int w = tid >> 6;
  const int m0 = blockIdx.x * 128;
  const int n0 = blockIdx.y * 128;
  const int wm = (w >> 1) * 64, wn = (w & 1) * 64;

  const int c0 = tid, c1 = tid + 256;
  const half_t* pA0 = A  + ((size_t)blockIdx.x * P1_ITERS * 512 + c0) * 8;
  const half_t* pA1 = A  + ((size_t)blockIdx.x * P1_ITERS * 512 + c1) * 8;
  const half_t* pB0 = Bm + ((size_t)blockIdx.y * P1_ITERS * 512 + c0) * 8;
  const half_t* pB1 = Bm + ((size_t)blockIdx.y * P1_ITERS * 512 + c1) * 8;

  floatx4 acc[4][4] = {};

  half8 ga0 = *(const half8*)(pA0);
  half8 ga1 = *(const half8*)(pA1);
  half8 gb0 = *(const half8*)(pB0);
  half8 gb1 = *(const half8*)(pB1);
  *(half8*)(SH + c0 * 8) = ga0;
  *(half8*)(SH + c1 * 8) = ga1;
  *(half8*)(SH + 8192 + c0 * 8) = gb0;
  *(half8*)(SH + 8192 + c1 * 8) = gb1;
  ga0 = *(const half8*)(pA0 + 4096);
  ga1 = *(const half8*)(pA1 + 4096);
  gb0 = *(const half8*)(pB0 + 4096);
  gb1 = *(const half8*)(pB1 + 4096);
  lds_barrier();

  #pragma unroll
  for (int i = 0; i < P1_ITERS; ++i) {
    const int cur = i & 1, nxt = cur ^ 1;
    half8 a[4], b[4];
    #pragma unroll
    for (int f = 0; f < 4; ++f) {
      a[f] = *(const half8*)(SH + cur * 4096 + (((wm >> 4) + f) * 64 + lane) * 8);
      b[f] = *(const half8*)(SH + 8192 + cur * 4096 + (((wn >> 4) + f) * 64 + lane) * 8);
    }
    if (i + 1 < P1_ITERS) {
      *(half8*)(SH + nxt * 4096 + c0 * 8) = ga0;
      *(half8*)(SH + nxt * 4096 + c1 * 8) = ga1;
      *(half8*)(SH + 8192 + nxt * 4096 + c0 * 8) = gb0;
      *(half8*)(SH + 8192 + nxt * 4096 + c1 * 8) = gb1;
    }
    if (i + 2 < P1_ITERS) {
      size_t ko = (size_t)(i + 2) * 4096;
      ga0 = *(const half8*)(pA0 + ko);
      ga1 = *(const half8*)(pA1 + ko);
      gb0 = *(const half8*)(pB0 + ko);
      gb1 = *(const half8*)(pB1 + ko);
    }
    #pragma unroll
    for (int mf = 0; mf < 4; ++mf)
      #pragma unroll
      for (int nf = 0; nf < 4; ++nf)
        acc[mf][nf] = __builtin_amdgcn_mfma_f32_16x16x32_f16(
            a[mf], b[nf], acc[mf][nf], 0, 0, 0);
    if (i + 1 < P1_ITERS) lds_barrier();
  }

  // Epilogue: acc -> LDS (fp16, +bias) -> row-contiguous coalesced stores.
  __syncthreads();
  const int col = lane & 15, qr = (lane >> 4) * 4;
  #pragma unroll
  for (int nf = 0; nf < 4; ++nf) {
    const int cloc = wn + nf * 16 + col;
    const int n = n0 + cloc;
    const float bv = (n < N3) ? bias[n] : 0.f;
    #pragma unroll
    for (int mf = 0; mf < 4; ++mf)
      #pragma unroll
      for (int r = 0; r < 4; ++r)
        SH[(wm + mf * 16 + qr + r) * 136 + cloc] =
            (half_t)(acc[mf][nf][r] + bv);
  }
  __syncthreads();
  const int row = tid >> 1, cc = (tid & 1) * 64;
  half_t* crow = C + (size_t)(m0 + row) * N3;
  #pragma unroll
  for (int j = 0; j < 8; ++j) {
    const int nn = n0 + cc + j * 8;
    half8 vv = *(const half8*)(SH + row * 136 + cc + j * 8);
    if (nn + 8 <= N3) {
      *(half8*)(crow + nn) = vv;
    } else if (nn < N3) {
      for (int e = 0; e < N3 - nn; ++e) crow[nn + e] = vv[e];
    }
  }
}

// ---- Phase 2a: recurrent GEMM partials, grid (50 g, 5 kz) x 768 thr. ----
// LDS-staged dedup + triple-buffered pipeline (round-12 verified optimum:
// depth r11-null, barrier-count r13-neg, block-split r14-neg all measured
// worse). Block stages A (8 KB) + W (9 KB) per kt ONCE into LDS; 12 waves
// = 3 nw x 4 mw consume contiguous 1024-B ds_read_b128 fragments.
__global__ __launch_bounds__(768, 3) void gru_gemm(
    const half_t* __restrict__ Ap_old,  // [75 kt][4 mw][2 mf][512] lane-major
    const half_t* __restrict__ Wp,      // [50][5][15][9][512] lane-major
    half_t* __restrict__ Gp)            // partials [5 kz][128 b][3 p][2400 j]
{
  __shared__ half_t S[3][8704];   // per buf: A halves 0..4095, W 4096..8703

  const int tid  = threadIdx.x;
  const int lane = tid & 63;
  const int w    = tid >> 6;        // 0..11
  const int mw   = w & 3;           // batch stripe (32 rows)
  const int nw   = w >> 2;          // unit-16 sub-group (0..2)
  const int g    = blockIdx.x;      // 0..49
  const int kz   = blockIdx.y;      // 0..4

  const half_t* Asrc = Ap_old + (size_t)kz * KZI * ACH;
  const half_t* Wsrc = Wp + (size_t)(g * KZ + kz) * KZI * WIT;

  const bool isA  = tid < 512;
  const bool has1 = tid < 320;
  const half_t* sb0 = isA ? (Asrc + tid * 8) : (Wsrc + (tid - 512) * 8);
  const int     st0 = isA ? ACH : WIT;
  const half_t* sb1 = Wsrc + (tid + 256) * 8;
  const int d0 = tid * 8;
  const int d1 = ACH + (tid + 256) * 8;

  half8 p0 = *(const half8*)(sb0);
  half8 q0{}; if (has1) q0 = *(const half8*)(sb1);
  half8 p1 = *(const half8*)(sb0 + st0);
  half8 q1{}; if (has1) q1 = *(const half8*)(sb1 + WIT);
  *(half8*)(&S[0][d0]) = p0;  if (has1) *(half8*)(&S[0][d1]) = q0;
  *(half8*)(&S[1][d0]) = p1;  if (has1) *(half8*)(&S[1][d1]) = q1;
  half8 rp0 = *(const half8*)(sb0 + 2 * (size_t)st0);
  half8 rq0{}; if (has1) rq0 = *(const half8*)(sb1 + 2 * (size_t)WIT);
  half8 rp1 = *(const half8*)(sb0 + 3 * (size_t)st0);
  half8 rq1{}; if (has1) rq1 = *(const half8*)(sb1 + 3 * (size_t)WIT);
  lds_barrier();

  floatx4 acc[2][3] = {};
  const int aoff0 = (mw * 2 + 0) * 512 + lane * 8;
  const int aoff1 = (mw * 2 + 1) * 512 + lane * 8;
  const int woff  = ACH + nw * 3 * 512 + lane * 8;

  #pragma unroll
  for (int i = 0; i < KZI; ++i) {
    const int cur = i % 3, wb = (i + 2) % 3;
    half8 a0 = *(const half8*)(&S[cur][aoff0]);
    half8 a1 = *(const half8*)(&S[cur][aoff1]);
    half8 b0 = *(const half8*)(&S[cur][woff]);
    half8 b1 = *(const half8*)(&S[cur][woff + 512]);
    half8 b2 = *(const half8*)(&S[cur][woff + 1024]);
    if (i + 2 < KZI) {
      *(half8*)(&S[wb][d0]) = rp0;
      if (has1) *(half8*)(&S[wb][d1]) = rq0;
    }
    rp0 = rp1; rq0 = rq1;
    if (i + 4 < KZI) {
      rp1 = *(const half8*)(sb0 + (size_t)(i + 4) * st0);
      if (has1) rq1 = *(const half8*)(sb1 + (size_t)(i + 4) * WIT);
    }
    acc[0][0] = __builtin_amdgcn_mfma_f32_16x16x32_f16(a0, b0, acc[0][0], 0, 0, 0);
    acc[1][0] = __builtin_amdgcn_mfma_f32_16x16x32_f16(a1, b0, acc[1][0], 0, 0, 0);
    acc[0][1] = __builtin_amdgcn_mfma_f32_16x16x32_f16(a0, b1, acc[0][1], 0, 0, 0);
    acc[1][1] = __builtin_amdgcn_mfma_f32_16x16x32_f16(a1, b1, acc[1][1], 0, 0, 0);
    acc[0][2] = __builtin_amdgcn_mfma_f32_16x16x32_f16(a0, b2, acc[0][2], 0, 0, 0);
    acc[1][2] = __builtin_amdgcn_mfma_f32_16x16x32_f16(a1, b2, acc[1][2], 0, 0, 0);
    if (i + 1 < KZI) lds_barrier();
  }

  const int j  = g * UG + nw * 16 + (lane & 15);
  const int wm = mw * 32;
  const int qr = (lane >> 4) * 4;
  #pragma unroll
  for (int mf = 0; mf < 2; ++mf)
    #pragma unroll
    for (int p = 0; p < 3; ++p)
      #pragma unroll
      for (int r = 0; r < 4; ++r) {
        const int b = wm + mf * 16 + qr + r;
        Gp[((size_t)(kz * B_ + b) * 3 + p) * H_ + j] = (half_t)acc[mf][p][r];
      }
}

// ---- Phase 2b: gate update. grid 300 x 256; thread = (b, 4 units). ----
__global__ void gru_gate(
    const half_t* __restrict__ Gp,      // [5][128][3][2400]
    const half_t* __restrict__ gx,      // [6144 x 7200]
    const float* __restrict__ hold,     // [B][H] fp32
    float* __restrict__ hnew,
    half_t* __restrict__ Ap_new,        // packed hh, lane-major
    const int* __restrict__ lengths,
    float* __restrict__ out,            // [B][H]
    int t)
{
  const int idx = blockIdx.x * 256 + threadIdx.x;   // over 128 * 600
  const int b = idx / 600;
  const int j = (idx - b * 600) * 4;

  floatx4 G[3] = {};
  #pragma unroll
  for (int kz = 0; kz < KZ; ++kz)
    #pragma unroll
    for (int p = 0; p < 3; ++p) {
      half4 v = *(const half4*)(Gp + ((size_t)(kz * B_ + b) * 3 + p) * H_ + j);
      #pragma unroll
      for (int e = 0; e < 4; ++e) G[p][e] += (float)v[e];
    }

  const size_t rx = ((size_t)b * S_ + t) * N3 + j;
  half4 hxr = *(const half4*)(gx + rx);
  half4 hxi = *(const half4*)(gx + rx + H_);
  half4 hxn = *(const half4*)(gx + rx + 2 * H_);
  floatx4 ho = *(const floatx4*)(hold + (size_t)b * H_ + j);

  floatx4 hv4;
  half4 ap4;
  #pragma unroll
  for (int e = 0; e < 4; ++e) {
    const float rg = 1.f / (1.f + __expf(-((float)hxr[e] + G[0][e])));
    const float ig = 1.f / (1.f + __expf(-((float)hxi[e] + G[1][e])));
    const float ta = (float)hxn[e] + rg * G[2][e];
    const float nn = 1.f - 2.f / (1.f + __expf(2.f * ta));  // tanh(ta)
    hv4[e] = (1.f - ig) * nn + ig * ho[e];
    ap4[e] = (half_t)hv4[e];
  }
  *(floatx4*)(hnew + (size_t)b * H_ + j) = hv4;

  // lane-major packed-A store: kt = j>>5; within chunk [mw][mf][lane][8]
  const int kt = j >> 5, ksub = j & 31;
  const int mwb = b >> 5, rb = b & 31, mfb = rb >> 4, fmb = rb & 15;
  const size_t pos = (size_t)kt * ACH + (mwb * 2 + mfb) * 512
                   + ((size_t)((ksub >> 3) * 16 + fmb)) * 8 + (ksub & 7);
  *(half4*)(Ap_new + pos) = ap4;

  int lc = lengths[b] - 1;
  lc = lc < 0 ? 0 : (lc > S_ - 1 ? S_ - 1 : lc);
  if (t == lc) *(floatx4*)(out + (size_t)b * H_ + j) = hv4;
}

extern "C" void kernel_launch(void* const* d_in, const int* in_sizes, int n_in,
                              void* d_out, int out_size, void* d_ws, size_t ws_size,
                              hipStream_t stream)
{
  const int*   tokens  = (const int*)d_in[0];
  const int*   lengths = (const int*)d_in[1];
  const float* emb = (const float*)d_in[2];
  const float* Wir = (const float*)d_in[3];
  const float* Wii = (const float*)d_in[4];
  const float* Win = (const float*)d_in[5];
  const float* bir = (const float*)d_in[6];
  const float* bii = (const float*)d_in[7];
  const float* bin = (const float*)d_in[8];
  const float* Whr = (const float*)d_in[9];
  const float* Whi = (const float*)d_in[10];
  const float* Whn = (const float*)d_in[11];
  float* out = (float*)d_out;

  char* ws = (char*)d_ws;
  size_t off = 0;
  auto alloc = [&](size_t bytes) {
    void* p = ws + off;
    off = (off + bytes + 255) & ~(size_t)255;
    return p;
  };
  half_t* xp   = (half_t*)alloc((size_t)48 * P1_ITERS * 512 * 8 * 2);   //  7.9 MB
  half_t* Wip  = (half_t*)alloc((size_t)NBP * P1_ITERS * 512 * 8 * 2);  //  9.3 MB
  half_t* Wp   = (half_t*)alloc((size_t)N3 * KH * 2);          // 34.6 MB packed
  float*  bias = (float*)alloc((size_t)N3 * 4);
  half_t* gx   = (half_t*)alloc((size_t)(B_ * S_) * N3 * 2);   // 88.5 MB
  half_t* Gp   = (half_t*)alloc((size_t)KZ * B_ * N3 * 2);     //  9.2 MB fp16
  float*  h0   = (float*)alloc((size_t)B_ * H_ * 4);           // ping-pong h [B][H]
  float*  h1   = (float*)alloc((size_t)B_ * H_ * 4);
  half_t* Ap0  = (half_t*)alloc((size_t)B_ * H_ * 2);          // packed hh
  half_t* Ap1  = (half_t*)alloc((size_t)B_ * H_ * 2);

  gather_cast_x<<<(6144 * 80) / 256, 256, 0, stream>>>(tokens, emb, xp);
  convert_wi<<<(7296 * 80) / 256, 256, 0, stream>>>(Wir, Wii, Win, bir, bii, bin,
                                                    Wip, bias);
  convert_wh<<<(N3 * 300 + 255) / 256, 256, 0, stream>>>(Whr, Whi, Whn, Wp);
  init_h<<<(B_ * H_) / 256, 256, 0, stream>>>(h0, Ap0);

  // Phase 1: gates_x = fp16( x @ W_i^T + b )   [6144 x 7200]
  gemm_x<<<dim3(48, NBP), 256, 0, stream>>>(xp, Wip, gx, bias);

  // Phase 2: 48 GRU steps x {250-block LDS-staged GEMM, 300-block gate}
  for (int t = 0; t < S_; ++t) {
    const half_t* ai = (t & 1) ? Ap1 : Ap0;
    half_t*       aw = (t & 1) ? Ap0 : Ap1;
    const float*  ho = (t & 1) ? h1  : h0;
    float*        hn = (t & 1) ? h0  : h1;
    gru_gemm<<<dim3(NG, KZ), 768, 0, stream>>>(ai, Wp, Gp);
    gru_gate<<<(B_ * H_ / 4) / 256, 256, 0, stream>>>(
        Gp, gx, ho, hn, aw, lengths, out, t);
  }
}